// Round 3
// baseline (368.330 us; speedup 1.0000x reference)
//
#include <hip/hip_runtime.h>

#define BATCH 8
#define NPTS  12000
#define FDIM  128
#define SDIM  16
#define ODIM  128
#define KDIM  (SDIM * FDIM)      // 2048
#define MTOT  (BATCH * NPTS)     // 96000

#define BM 128
#define BK 64
#define LDA 72                   // BK + 8 pad (bf16 elements) -> 144 B row stride

#define NTILES 94                // ceil(12000 / 128)
#define XELEMS (BATCH * NPTS * FDIM)   // 12,288,000
#define WELEMS (ODIM * KDIM)           // 262,144
#define XBYTES ((size_t)XELEMS * 2)
#define WBYTES ((size_t)WELEMS * 2)

typedef __bf16 bf16x4 __attribute__((ext_vector_type(4)));
typedef __bf16 bf16x8 __attribute__((ext_vector_type(8)));
typedef float  f32x4  __attribute__((ext_vector_type(4)));
typedef float  f32x8  __attribute__((ext_vector_type(8)));

// ---------------- pre-pass: fp32 -> bf16 ----------------
__global__ __launch_bounds__(256)
void cvt_f32_bf16(const float* __restrict__ src, __bf16* __restrict__ dst, int n4) {
    int i = blockIdx.x * blockDim.x + threadIdx.x;
    const int stride = gridDim.x * blockDim.x;
    for (; i < n4; i += stride) {
        const float4 v = reinterpret_cast<const float4*>(src)[i];
        bf16x4 h;
        h[0] = (__bf16)v.x; h[1] = (__bf16)v.y;
        h[2] = (__bf16)v.z; h[3] = (__bf16)v.w;
        reinterpret_cast<bf16x4*>(dst)[i] = h;
    }
}

// ---------------- main GEMM: bf16 inputs, XCD-batch locality, reg prefetch ----------------
__global__ __launch_bounds__(256, 4)
void spiral_gemm_bf16(const __bf16* __restrict__ xb,    // (B, N, F) bf16 (ws)
                      const __bf16* __restrict__ Wb,    // (OUT, K) bf16 (ws)
                      const float*  __restrict__ bias,  // (OUT,) fp32
                      const int*    __restrict__ idx,   // (N, S) int32
                      const float*  __restrict__ zp,    // (N,) fp32
                      float*        __restrict__ out)   // (B, N, OUT) fp32
{
    __shared__ __bf16 As[BM * LDA];
    __shared__ __bf16 Ws[ODIM * LDA];

    const int tid   = threadIdx.x;
    const int wave  = tid >> 6;
    const int lane  = tid & 63;
    const int batch = blockIdx.x & 7;          // round-robin -> same XCD per batch
    const int n0    = (blockIdx.x >> 3) * BM;  // n-tile within the batch

    const int srow   = tid >> 3;   // 0..31
    const int schunk = tid & 7;    // 0..7

    const __bf16* xbase = xb + (size_t)batch * (NPTS * FDIM);

    int a_nn[4];
#pragma unroll
    for (int p = 0; p < 4; ++p) {
        const int n = n0 + srow + p * 32;
        a_nn[p] = n < NPTS ? n : NPTS - 1;     // clamp; last tile is partial
    }

    f32x4 acc[4][4];
#pragma unroll
    for (int i = 0; i < 4; ++i)
#pragma unroll
        for (int j = 0; j < 4; ++j)
            acc[i][j] = f32x4{0.f, 0.f, 0.f, 0.f};

    uint4 pa[4], pw[4];
    auto stage = [&](int kt) {
#pragma unroll
        for (int p = 0; p < 4; ++p) {
            const int s  = kt >> 1;
            const int f0 = (kt & 1) * BK;
            const int g  = idx[a_nn[p] * SDIM + s];
            pa[p] = *reinterpret_cast<const uint4*>(
                xbase + (size_t)g * FDIM + f0 + schunk * 8);
            pw[p] = *reinterpret_cast<const uint4*>(
                Wb + (size_t)(srow + p * 32) * KDIM + kt * BK + schunk * 8);
        }
    };

    const int wm   = (wave >> 1) * 64;
    const int wn   = (wave & 1) * 64;
    const int lrow = lane & 15;
    const int quad = lane >> 4;

    stage(0);
    for (int kt = 0; kt < KDIM / BK; ++kt) {   // 32 iterations
        // write prefetched regs to LDS (vmcnt wait lands here, after prior MFMAs)
#pragma unroll
        for (int p = 0; p < 4; ++p) {
            const int r = srow + p * 32;
            *reinterpret_cast<uint4*>(&As[r * LDA + schunk * 8]) = pa[p];
            *reinterpret_cast<uint4*>(&Ws[r * LDA + schunk * 8]) = pw[p];
        }
        __syncthreads();
        if (kt + 1 < KDIM / BK) stage(kt + 1);  // loads fly during MFMA below
#pragma unroll
        for (int kk = 0; kk < 2; ++kk) {
            const int koff = kk * 32 + quad * 8;
            bf16x8 a[4], b[4];
#pragma unroll
            for (int i = 0; i < 4; ++i)
                a[i] = *reinterpret_cast<const bf16x8*>(
                    &As[(wm + i * 16 + lrow) * LDA + koff]);
#pragma unroll
            for (int j = 0; j < 4; ++j)
                b[j] = *reinterpret_cast<const bf16x8*>(
                    &Ws[(wn + j * 16 + lrow) * LDA + koff]);
#pragma unroll
            for (int i = 0; i < 4; ++i)
#pragma unroll
                for (int j = 0; j < 4; ++j)
                    acc[i][j] = __builtin_amdgcn_mfma_f32_16x16x32_bf16(
                        a[i], b[j], acc[i][j], 0, 0, 0);
        }
        if (kt + 1 < KDIM / BK) __syncthreads();  // done reading before next overwrite
    }

    // epilogue: bias + relu + zero_padding; C/D: col=lane&15, row=quad*4+reg
#pragma unroll
    for (int i = 0; i < 4; ++i) {
#pragma unroll
        for (int r = 0; r < 4; ++r) {
            const int row = wm + i * 16 + quad * 4 + r;
            const int n   = n0 + row;
            if (n < NPTS) {
                const float z = zp[n];
                float* orow   = out + ((size_t)batch * NPTS + n) * ODIM;
#pragma unroll
                for (int j = 0; j < 4; ++j) {
                    const int col = wn + j * 16 + lrow;
                    float v = acc[i][j][r] + bias[col];
                    v = fmaxf(v, 0.f);
                    orow[col] = v * z;
                }
            }
        }
    }
}

// ---------------- fallback (round-2 kernel): fp32 direct, no ws ----------------
__global__ __launch_bounds__(256, 2)
void spiral_gemm_fp32(const float* __restrict__ x, const float* __restrict__ W,
                      const float* __restrict__ bias, const int* __restrict__ idx,
                      const float* __restrict__ zp, float* __restrict__ out)
{
    __shared__ __bf16 As[BM * LDA];
    __shared__ __bf16 Ws[ODIM * LDA];
    const int tid = threadIdx.x, wave = tid >> 6, lane = tid & 63;
    const int m0 = blockIdx.x * BM;
    const int srow = tid >> 3, schunk = tid & 7;
    int a_n[4]; const float* a_xb[4];
#pragma unroll
    for (int p = 0; p < 4; ++p) {
        int m = m0 + srow + p * 32, bb = m / NPTS;
        a_n[p] = m - bb * NPTS; a_xb[p] = x + (size_t)bb * (NPTS * FDIM);
    }
    f32x4 acc[4][4];
#pragma unroll
    for (int i = 0; i < 4; ++i)
#pragma unroll
        for (int j = 0; j < 4; ++j) acc[i][j] = f32x4{0.f,0.f,0.f,0.f};
    const int wm = (wave >> 1) * 64, wn = (wave & 1) * 64;
    const int lrow = lane & 15, quad = lane >> 4;
    for (int kt = 0; kt < KDIM / BK; ++kt) {
        const int s = kt >> 1, f0 = (kt & 1) * BK;
        __syncthreads();
#pragma unroll
        for (int p = 0; p < 4; ++p) {
            const int r = srow + p * 32;
            const int g = idx[a_n[p] * SDIM + s];
            const f32x8 v = *reinterpret_cast<const f32x8*>(
                a_xb[p] + (size_t)g * FDIM + f0 + schunk * 8);
            bf16x8 h;
#pragma unroll
            for (int e = 0; e < 8; ++e) h[e] = (__bf16)v[e];
            *reinterpret_cast<bf16x8*>(&As[r * LDA + schunk * 8]) = h;
            const f32x8 w = *reinterpret_cast<const f32x8*>(
                W + (size_t)r * KDIM + kt * BK + schunk * 8);
            bf16x8 hw;
#pragma unroll
            for (int e = 0; e < 8; ++e) hw[e] = (__bf16)w[e];
            *reinterpret_cast<bf16x8*>(&Ws[r * LDA + schunk * 8]) = hw;
        }
        __syncthreads();
#pragma unroll
        for (int kk = 0; kk < 2; ++kk) {
            const int koff = kk * 32 + quad * 8;
            bf16x8 a[4], b[4];
#pragma unroll
            for (int i = 0; i < 4; ++i)
                a[i] = *reinterpret_cast<const bf16x8*>(&As[(wm + i*16 + lrow)*LDA + koff]);
#pragma unroll
            for (int j = 0; j < 4; ++j)
                b[j] = *reinterpret_cast<const bf16x8*>(&Ws[(wn + j*16 + lrow)*LDA + koff]);
#pragma unroll
            for (int i = 0; i < 4; ++i)
#pragma unroll
                for (int j = 0; j < 4; ++j)
                    acc[i][j] = __builtin_amdgcn_mfma_f32_16x16x32_bf16(a[i], b[j], acc[i][j], 0,0,0);
        }
    }
#pragma unroll
    for (int i = 0; i < 4; ++i)
#pragma unroll
        for (int r = 0; r < 4; ++r) {
            const int row = wm + i * 16 + quad * 4 + r;
            const int m = m0 + row, bb = m / NPTS, nn = m - bb * NPTS;
            const float z = zp[nn];
            float* orow = out + (size_t)m * ODIM;
#pragma unroll
            for (int j = 0; j < 4; ++j) {
                const int col = wn + j * 16 + lrow;
                float v = acc[i][j][r] + bias[col];
                orow[col] = fmaxf(v, 0.f) * z;
            }
        }
}

extern "C" void kernel_launch(void* const* d_in, const int* in_sizes, int n_in,
                              void* d_out, int out_size, void* d_ws, size_t ws_size,
                              hipStream_t stream) {
    const float* x    = (const float*)d_in[0];
    const float* W    = (const float*)d_in[1];
    const float* bias = (const float*)d_in[2];
    const int*   idx  = (const int*)d_in[3];
    const float* zp   = (const float*)d_in[4];
    float*       out  = (float*)d_out;

    if (ws_size >= XBYTES + WBYTES) {
        __bf16* xb = (__bf16*)d_ws;
        __bf16* Wb = (__bf16*)((char*)d_ws + XBYTES);
        cvt_f32_bf16<<<dim3(1024), dim3(256), 0, stream>>>(x, xb, XELEMS / 4);
        cvt_f32_bf16<<<dim3(256),  dim3(256), 0, stream>>>(W, Wb, WELEMS / 4);
        spiral_gemm_bf16<<<dim3(BATCH * NTILES), dim3(256), 0, stream>>>(
            xb, Wb, bias, idx, zp, out);
    } else {
        spiral_gemm_fp32<<<dim3(MTOT / BM), dim3(256), 0, stream>>>(
            x, W, bias, idx, zp, out);
    }
}

// Round 4
// 198.040 us; speedup vs baseline: 1.8599x; 1.8599x over previous
//
#include <hip/hip_runtime.h>

#define BATCH 8
#define NPTS  12000
#define FDIM  128
#define SDIM  16
#define ODIM  128
#define KDIM  (SDIM * FDIM)      // 2048
#define MTOT  (BATCH * NPTS)     // 96000

#define BM 128
#define BK 64
#define LDA 72                   // BK + 8 pad (bf16 elements) -> 144 B row stride

#define NTILES 94                // ceil(12000 / 128)
#define XELEMS (BATCH * NPTS * FDIM)   // 12,288,000
#define WELEMS (ODIM * KDIM)           // 262,144
#define XBYTES ((size_t)XELEMS * 2)
#define WBYTES ((size_t)WELEMS * 2)
#define XN4    (XELEMS / 4)
#define WN4    (WELEMS / 4)

typedef __bf16 bf16x4 __attribute__((ext_vector_type(4)));
typedef __bf16 bf16x8 __attribute__((ext_vector_type(8)));
typedef float  f32x4  __attribute__((ext_vector_type(4)));
typedef float  f32x8  __attribute__((ext_vector_type(8)));

// ---------------- pre-pass: fp32 -> bf16 (x and W in one launch) ----------------
__global__ __launch_bounds__(256)
void cvt_f32_bf16(const float* __restrict__ x, const float* __restrict__ W,
                  __bf16* __restrict__ xb, __bf16* __restrict__ Wb) {
    int i = blockIdx.x * blockDim.x + threadIdx.x;
    const int stride = gridDim.x * blockDim.x;
    for (; i < XN4 + WN4; i += stride) {
        const float* src; __bf16* dst; int j;
        if (i < XN4) { src = x; dst = xb; j = i; }
        else         { src = W; dst = Wb; j = i - XN4; }
        const float4 v = reinterpret_cast<const float4*>(src)[j];
        bf16x4 h;
        h[0] = (__bf16)v.x; h[1] = (__bf16)v.y;
        h[2] = (__bf16)v.z; h[3] = (__bf16)v.w;
        reinterpret_cast<bf16x4*>(dst)[j] = h;
    }
}

// ---------------- main GEMM: bf16 inputs, XCD-batch locality ----------------
// No register prefetch (round-3 spill lesson); __launch_bounds__(256,3) keeps
// VGPR budget at ~170 so nothing can spill.
__global__ __launch_bounds__(256, 3)
void spiral_gemm_bf16(const __bf16* __restrict__ xb,    // (B, N, F) bf16 (ws)
                      const __bf16* __restrict__ Wb,    // (OUT, K) bf16 (ws)
                      const float*  __restrict__ bias,  // (OUT,) fp32
                      const int*    __restrict__ idx,   // (N, S) int32
                      const float*  __restrict__ zp,    // (N,) fp32
                      float*        __restrict__ out)   // (B, N, OUT) fp32
{
    __shared__ __bf16 As[BM * LDA];
    __shared__ __bf16 Ws[ODIM * LDA];

    const int tid   = threadIdx.x;
    const int wave  = tid >> 6;
    const int lane  = tid & 63;
    const int batch = blockIdx.x & 7;          // round-robin -> same XCD per batch
    const int n0    = (blockIdx.x >> 3) * BM;  // n-tile within the batch

    const int srow   = tid >> 3;   // 0..31
    const int schunk = tid & 7;    // 0..7

    const __bf16* xbase = xb + (size_t)batch * (NPTS * FDIM);

    int a_nn[4];
#pragma unroll
    for (int p = 0; p < 4; ++p) {
        const int n = n0 + srow + p * 32;
        a_nn[p] = n < NPTS ? n : NPTS - 1;     // clamp; last tile is partial
    }

    f32x4 acc[4][4];
#pragma unroll
    for (int i = 0; i < 4; ++i)
#pragma unroll
        for (int j = 0; j < 4; ++j)
            acc[i][j] = f32x4{0.f, 0.f, 0.f, 0.f};

    const int wm   = (wave >> 1) * 64;   // 2x2 waves, each 64x64
    const int wn   = (wave & 1) * 64;
    const int lrow = lane & 15;
    const int quad = lane >> 4;

    for (int kt = 0; kt < KDIM / BK; ++kt) {   // 32 iterations
        const int s  = kt >> 1;                // spiral neighbor index
        const int f0 = (kt & 1) * BK;          // 0 or 64 within the gathered row
        __syncthreads();
        // --- stage gathered A tile + W tile: direct load -> LDS ---
#pragma unroll
        for (int p = 0; p < 4; ++p) {
            const int r = srow + p * 32;
            const int g = idx[a_nn[p] * SDIM + s];
            const uint4 va = *reinterpret_cast<const uint4*>(
                xbase + (size_t)g * FDIM + f0 + schunk * 8);
            *reinterpret_cast<uint4*>(&As[r * LDA + schunk * 8]) = va;
            const uint4 vw = *reinterpret_cast<const uint4*>(
                Wb + (size_t)r * KDIM + kt * BK + schunk * 8);
            *reinterpret_cast<uint4*>(&Ws[r * LDA + schunk * 8]) = vw;
        }
        __syncthreads();
        // --- compute: 2 k-steps of 32, 16 MFMAs each ---
#pragma unroll
        for (int kk = 0; kk < 2; ++kk) {
            const int koff = kk * 32 + quad * 8;
            bf16x8 a[4], b[4];
#pragma unroll
            for (int i = 0; i < 4; ++i)
                a[i] = *reinterpret_cast<const bf16x8*>(
                    &As[(wm + i * 16 + lrow) * LDA + koff]);
#pragma unroll
            for (int j = 0; j < 4; ++j)
                b[j] = *reinterpret_cast<const bf16x8*>(
                    &Ws[(wn + j * 16 + lrow) * LDA + koff]);
#pragma unroll
            for (int i = 0; i < 4; ++i)
#pragma unroll
                for (int j = 0; j < 4; ++j)
                    acc[i][j] = __builtin_amdgcn_mfma_f32_16x16x32_bf16(
                        a[i], b[j], acc[i][j], 0, 0, 0);
        }
    }

    // epilogue: bias + relu + zero_padding; C/D: col=lane&15, row=quad*4+reg
#pragma unroll
    for (int i = 0; i < 4; ++i) {
#pragma unroll
        for (int r = 0; r < 4; ++r) {
            const int row = wm + i * 16 + quad * 4 + r;
            const int n   = n0 + row;
            if (n < NPTS) {
                const float z = zp[n];
                float* orow   = out + ((size_t)batch * NPTS + n) * ODIM;
#pragma unroll
                for (int j = 0; j < 4; ++j) {
                    const int col = wn + j * 16 + lrow;
                    float v = acc[i][j][r] + bias[col];
                    v = fmaxf(v, 0.f);
                    orow[col] = v * z;
                }
            }
        }
    }
}

// ---------------- fallback (round-2 kernel): fp32 direct, no ws ----------------
__global__ __launch_bounds__(256, 2)
void spiral_gemm_fp32(const float* __restrict__ x, const float* __restrict__ W,
                      const float* __restrict__ bias, const int* __restrict__ idx,
                      const float* __restrict__ zp, float* __restrict__ out)
{
    __shared__ __bf16 As[BM * LDA];
    __shared__ __bf16 Ws[ODIM * LDA];
    const int tid = threadIdx.x, wave = tid >> 6, lane = tid & 63;
    const int m0 = blockIdx.x * BM;
    const int srow = tid >> 3, schunk = tid & 7;
    int a_n[4]; const float* a_xb[4];
#pragma unroll
    for (int p = 0; p < 4; ++p) {
        int m = m0 + srow + p * 32, bb = m / NPTS;
        a_n[p] = m - bb * NPTS; a_xb[p] = x + (size_t)bb * (NPTS * FDIM);
    }
    f32x4 acc[4][4];
#pragma unroll
    for (int i = 0; i < 4; ++i)
#pragma unroll
        for (int j = 0; j < 4; ++j) acc[i][j] = f32x4{0.f,0.f,0.f,0.f};
    const int wm = (wave >> 1) * 64, wn = (wave & 1) * 64;
    const int lrow = lane & 15, quad = lane >> 4;
    for (int kt = 0; kt < KDIM / BK; ++kt) {
        const int s = kt >> 1, f0 = (kt & 1) * BK;
        __syncthreads();
#pragma unroll
        for (int p = 0; p < 4; ++p) {
            const int r = srow + p * 32;
            const int g = idx[a_n[p] * SDIM + s];
            const f32x8 v = *reinterpret_cast<const f32x8*>(
                a_xb[p] + (size_t)g * FDIM + f0 + schunk * 8);
            bf16x8 h;
#pragma unroll
            for (int e = 0; e < 8; ++e) h[e] = (__bf16)v[e];
            *reinterpret_cast<bf16x8*>(&As[r * LDA + schunk * 8]) = h;
            const f32x8 w = *reinterpret_cast<const f32x8*>(
                W + (size_t)r * KDIM + kt * BK + schunk * 8);
            bf16x8 hw;
#pragma unroll
            for (int e = 0; e < 8; ++e) hw[e] = (__bf16)w[e];
            *reinterpret_cast<bf16x8*>(&Ws[r * LDA + schunk * 8]) = hw;
        }
        __syncthreads();
#pragma unroll
        for (int kk = 0; kk < 2; ++kk) {
            const int koff = kk * 32 + quad * 8;
            bf16x8 a[4], b[4];
#pragma unroll
            for (int i = 0; i < 4; ++i)
                a[i] = *reinterpret_cast<const bf16x8*>(&As[(wm + i*16 + lrow)*LDA + koff]);
#pragma unroll
            for (int j = 0; j < 4; ++j)
                b[j] = *reinterpret_cast<const bf16x8*>(&Ws[(wn + j*16 + lrow)*LDA + koff]);
#pragma unroll
            for (int i = 0; i < 4; ++i)
#pragma unroll
                for (int j = 0; j < 4; ++j)
                    acc[i][j] = __builtin_amdgcn_mfma_f32_16x16x32_bf16(a[i], b[j], acc[i][j], 0,0,0);
        }
    }
#pragma unroll
    for (int i = 0; i < 4; ++i)
#pragma unroll
        for (int r = 0; r < 4; ++r) {
            const int row = wm + i * 16 + quad * 4 + r;
            const int m = m0 + row, bb = m / NPTS, nn = m - bb * NPTS;
            const float z = zp[nn];
            float* orow = out + (size_t)m * ODIM;
#pragma unroll
            for (int j = 0; j < 4; ++j) {
                const int col = wn + j * 16 + lrow;
                float v = acc[i][j][r] + bias[col];
                orow[col] = fmaxf(v, 0.f) * z;
            }
        }
}

extern "C" void kernel_launch(void* const* d_in, const int* in_sizes, int n_in,
                              void* d_out, int out_size, void* d_ws, size_t ws_size,
                              hipStream_t stream) {
    const float* x    = (const float*)d_in[0];
    const float* W    = (const float*)d_in[1];
    const float* bias = (const float*)d_in[2];
    const int*   idx  = (const int*)d_in[3];
    const float* zp   = (const float*)d_in[4];
    float*       out  = (float*)d_out;

    if (ws_size >= XBYTES + WBYTES) {
        __bf16* xb = (__bf16*)d_ws;
        __bf16* Wb = (__bf16*)((char*)d_ws + XBYTES);
        cvt_f32_bf16<<<dim3(1024), dim3(256), 0, stream>>>(x, W, xb, Wb);
        spiral_gemm_bf16<<<dim3(BATCH * NTILES), dim3(256), 0, stream>>>(
            xb, Wb, bias, idx, zp, out);
    } else {
        spiral_gemm_fp32<<<dim3(MTOT / BM), dim3(256), 0, stream>>>(
            x, W, bias, idx, zp, out);
    }
}

// Round 5
// 165.166 us; speedup vs baseline: 2.2301x; 1.1990x over previous
//
#include <hip/hip_runtime.h>

#define BATCH 8
#define NPTS  12000
#define FDIM  128
#define SDIM  16
#define ODIM  128
#define KDIM  (SDIM * FDIM)      // 2048
#define MTOT  (BATCH * NPTS)     // 96000

#define BM 128
#define BK 64                    // unpadded: row stride 64 bf16 = 128 B

#define NTILES 94                // ceil(12000 / 128)
#define XELEMS (BATCH * NPTS * FDIM)   // 12,288,000
#define WELEMS (ODIM * KDIM)           // 262,144
#define XBYTES ((size_t)XELEMS * 2)
#define WBYTES ((size_t)WELEMS * 2)
#define XN4    (XELEMS / 4)
#define WN4    (WELEMS / 4)

typedef __bf16 bf16x4 __attribute__((ext_vector_type(4)));
typedef __bf16 bf16x8 __attribute__((ext_vector_type(8)));
typedef float  f32x4  __attribute__((ext_vector_type(4)));
typedef float  f32x8  __attribute__((ext_vector_type(8)));

#define AS1(p) ((const __attribute__((address_space(1))) void*)(p))
#define AS3(p) ((__attribute__((address_space(3))) void*)(p))

// ---------------- pre-pass: fp32 -> bf16 (x and W in one launch) ----------------
__global__ __launch_bounds__(256)
void cvt_f32_bf16(const float* __restrict__ x, const float* __restrict__ W,
                  __bf16* __restrict__ xb, __bf16* __restrict__ Wb) {
    int i = blockIdx.x * blockDim.x + threadIdx.x;
    const int stride = gridDim.x * blockDim.x;
    for (; i < XN4 + WN4; i += stride) {
        const float* src; __bf16* dst; int j;
        if (i < XN4) { src = x; dst = xb; j = i; }
        else         { src = W; dst = Wb; j = i - XN4; }
        const float4 v = reinterpret_cast<const float4*>(src)[j];
        bf16x4 h;
        h[0] = (__bf16)v.x; h[1] = (__bf16)v.y;
        h[2] = (__bf16)v.z; h[3] = (__bf16)v.w;
        reinterpret_cast<bf16x4*>(dst)[j] = h;
    }
}

// ---------------- main GEMM: global_load_lds staging + XOR-swizzled LDS ----------------
// LDS layout: row-major [row][chunk], chunk = 16 B (8 bf16). Physical chunk of
// logical chunk c at row r is c ^ (r & 7). global_load_lds writes wave-uniform
// base + lane*16: lane -> (row r0+(lane>>3), phys chunk lane&7), so each lane
// fetches the global data for logical chunk (lane&7)^(lane>>3).
__global__ __launch_bounds__(256, 4)
void spiral_gemm_bf16(const __bf16* __restrict__ xb,    // (B, N, F) bf16 (ws)
                      const __bf16* __restrict__ Wb,    // (OUT, K) bf16 (ws)
                      const float*  __restrict__ bias,  // (OUT,) fp32
                      const int*    __restrict__ idx,   // (N, S) int32
                      const float*  __restrict__ zp,    // (N,) fp32
                      float*        __restrict__ out)   // (B, N, OUT) fp32
{
    __shared__ __bf16 As[BM * BK];    // 16 KB
    __shared__ __bf16 Ws[ODIM * BK];  // 16 KB

    const int tid   = threadIdx.x;
    const int wave  = tid >> 6;
    const int lane  = tid & 63;
    const int batch = blockIdx.x & 7;          // round-robin -> same XCD per batch
    const int n0    = (blockIdx.x >> 3) * BM;

    const int lrow8 = lane >> 3;               // row within the 8-row wave pass
    const int clog  = (lane & 7) ^ lrow8;      // logical 16B chunk this lane fetches

    const __bf16* xbase = xb + (size_t)batch * (NPTS * FDIM);

    // rows handled by this lane (one per pass p), and idx prefetch registers
    int nn[4], gcur[4], gnext[4];
#pragma unroll
    for (int p = 0; p < 4; ++p) {
        const int r = (p * 4 + wave) * 8 + lrow8;
        int n = n0 + r;
        nn[p]   = n < NPTS ? n : NPTS - 1;     // clamp; last tile partial
        gcur[p] = idx[nn[p] * SDIM + 0];
    }

    f32x4 acc[4][4];
#pragma unroll
    for (int i = 0; i < 4; ++i)
#pragma unroll
        for (int j = 0; j < 4; ++j)
            acc[i][j] = f32x4{0.f, 0.f, 0.f, 0.f};

    const int wm   = (wave >> 1) * 64;
    const int wn   = (wave & 1) * 64;
    const int lrow = lane & 15;
    const int quad = lane >> 4;

    for (int kt = 0; kt < KDIM / BK; ++kt) {   // 32 iterations
        const int f0 = (kt & 1) * BK;          // half-row select within gathered row
        __syncthreads();                        // prior reads done before overwrite
        // --- async staging: 4 passes x (As + Ws), 1 KB per wave per issue ---
#pragma unroll
        for (int p = 0; p < 4; ++p) {
            const int r0 = (p * 4 + wave) * 8;           // wave-uniform row base
            const __bf16* ga = xbase + (size_t)gcur[p] * FDIM + f0 + clog * 8;
            __builtin_amdgcn_global_load_lds(AS1(ga), AS3(&As[r0 * BK]), 16, 0, 0);
            const __bf16* gw = Wb + (size_t)(r0 + lrow8) * KDIM + kt * BK + clog * 8;
            __builtin_amdgcn_global_load_lds(AS1(gw), AS3(&Ws[r0 * BK]), 16, 0, 0);
        }
        // prefetch idx for the next spiral neighbor while loads are in flight
        if ((kt & 1) && kt < KDIM / BK - 1) {
            const int snext = (kt >> 1) + 1;
#pragma unroll
            for (int p = 0; p < 4; ++p) gnext[p] = idx[nn[p] * SDIM + snext];
        }
        __syncthreads();                        // vmcnt(0) drain: tiles visible
        // --- compute: 2 k-steps of 32, 16 MFMAs each ---
#pragma unroll
        for (int kk = 0; kk < 2; ++kk) {
            const int ph = (kk * 4 + quad) ^ (lrow & 7);  // swizzled chunk
            bf16x8 a[4], b[4];
#pragma unroll
            for (int i = 0; i < 4; ++i)
                a[i] = *reinterpret_cast<const bf16x8*>(
                    &As[(wm + i * 16 + lrow) * BK + ph * 8]);
#pragma unroll
            for (int j = 0; j < 4; ++j)
                b[j] = *reinterpret_cast<const bf16x8*>(
                    &Ws[(wn + j * 16 + lrow) * BK + ph * 8]);
#pragma unroll
            for (int i = 0; i < 4; ++i)
#pragma unroll
                for (int j = 0; j < 4; ++j)
                    acc[i][j] = __builtin_amdgcn_mfma_f32_16x16x32_bf16(
                        a[i], b[j], acc[i][j], 0, 0, 0);
        }
        if (kt & 1) {
#pragma unroll
            for (int p = 0; p < 4; ++p) gcur[p] = gnext[p];
        }
    }

    // epilogue: bias + relu + zero_padding; C/D: col=lane&15, row=quad*4+reg
#pragma unroll
    for (int i = 0; i < 4; ++i) {
#pragma unroll
        for (int r = 0; r < 4; ++r) {
            const int row = wm + i * 16 + quad * 4 + r;
            const int n   = n0 + row;
            if (n < NPTS) {
                const float z = zp[n];
                float* orow   = out + ((size_t)batch * NPTS + n) * ODIM;
#pragma unroll
                for (int j = 0; j < 4; ++j) {
                    const int col = wn + j * 16 + lrow;
                    float v = acc[i][j][r] + bias[col];
                    v = fmaxf(v, 0.f);
                    orow[col] = v * z;
                }
            }
        }
    }
}

// ---------------- fallback: fp32 direct, no ws (round-2 kernel) ----------------
#define LDA 72
__global__ __launch_bounds__(256, 2)
void spiral_gemm_fp32(const float* __restrict__ x, const float* __restrict__ W,
                      const float* __restrict__ bias, const int* __restrict__ idx,
                      const float* __restrict__ zp, float* __restrict__ out)
{
    __shared__ __bf16 Asf[BM * LDA];
    __shared__ __bf16 Wsf[ODIM * LDA];
    const int tid = threadIdx.x, wave = tid >> 6, lane = tid & 63;
    const int m0 = blockIdx.x * BM;
    const int srow = tid >> 3, schunk = tid & 7;
    int a_n[4]; const float* a_xb[4];
#pragma unroll
    for (int p = 0; p < 4; ++p) {
        int m = m0 + srow + p * 32, bb = m / NPTS;
        a_n[p] = m - bb * NPTS; a_xb[p] = x + (size_t)bb * (NPTS * FDIM);
    }
    f32x4 acc[4][4];
#pragma unroll
    for (int i = 0; i < 4; ++i)
#pragma unroll
        for (int j = 0; j < 4; ++j) acc[i][j] = f32x4{0.f,0.f,0.f,0.f};
    const int wm = (wave >> 1) * 64, wn = (wave & 1) * 64;
    const int lrow = lane & 15, quad = lane >> 4;
    for (int kt = 0; kt < KDIM / BK; ++kt) {
        const int s = kt >> 1, f0 = (kt & 1) * BK;
        __syncthreads();
#pragma unroll
        for (int p = 0; p < 4; ++p) {
            const int r = srow + p * 32;
            const int g = idx[a_n[p] * SDIM + s];
            const f32x8 v = *reinterpret_cast<const f32x8*>(
                a_xb[p] + (size_t)g * FDIM + f0 + schunk * 8);
            bf16x8 h;
#pragma unroll
            for (int e = 0; e < 8; ++e) h[e] = (__bf16)v[e];
            *reinterpret_cast<bf16x8*>(&Asf[r * LDA + schunk * 8]) = h;
            const f32x8 w = *reinterpret_cast<const f32x8*>(
                W + (size_t)r * KDIM + kt * BK + schunk * 8);
            bf16x8 hw;
#pragma unroll
            for (int e = 0; e < 8; ++e) hw[e] = (__bf16)w[e];
            *reinterpret_cast<bf16x8*>(&Wsf[r * LDA + schunk * 8]) = hw;
        }
        __syncthreads();
#pragma unroll
        for (int kk = 0; kk < 2; ++kk) {
            const int koff = kk * 32 + quad * 8;
            bf16x8 a[4], b[4];
#pragma unroll
            for (int i = 0; i < 4; ++i)
                a[i] = *reinterpret_cast<const bf16x8*>(&Asf[(wm + i*16 + lrow)*LDA + koff]);
#pragma unroll
            for (int j = 0; j < 4; ++j)
                b[j] = *reinterpret_cast<const bf16x8*>(&Wsf[(wn + j*16 + lrow)*LDA + koff]);
#pragma unroll
            for (int i = 0; i < 4; ++i)
#pragma unroll
                for (int j = 0; j < 4; ++j)
                    acc[i][j] = __builtin_amdgcn_mfma_f32_16x16x32_bf16(a[i], b[j], acc[i][j], 0,0,0);
        }
    }
#pragma unroll
    for (int i = 0; i < 4; ++i)
#pragma unroll
        for (int r = 0; r < 4; ++r) {
            const int row = wm + i * 16 + quad * 4 + r;
            const int m = m0 + row, bb = m / NPTS, nnn = m - bb * NPTS;
            const float z = zp[nnn];
            float* orow = out + (size_t)m * ODIM;
#pragma unroll
            for (int j = 0; j < 4; ++j) {
                const int col = wn + j * 16 + lrow;
                float v = acc[i][j][r] + bias[col];
                orow[col] = fmaxf(v, 0.f) * z;
            }
        }
}

extern "C" void kernel_launch(void* const* d_in, const int* in_sizes, int n_in,
                              void* d_out, int out_size, void* d_ws, size_t ws_size,
                              hipStream_t stream) {
    const float* x    = (const float*)d_in[0];
    const float* W    = (const float*)d_in[1];
    const float* bias = (const float*)d_in[2];
    const int*   idx  = (const int*)d_in[3];
    const float* zp   = (const float*)d_in[4];
    float*       out  = (float*)d_out;

    if (ws_size >= XBYTES + WBYTES) {
        __bf16* xb = (__bf16*)d_ws;
        __bf16* Wb = (__bf16*)((char*)d_ws + XBYTES);
        cvt_f32_bf16<<<dim3(1024), dim3(256), 0, stream>>>(x, W, xb, Wb);
        spiral_gemm_bf16<<<dim3(BATCH * NTILES), dim3(256), 0, stream>>>(
            xb, Wb, bias, idx, zp, out);
    } else {
        spiral_gemm_fp32<<<dim3(MTOT / BM), dim3(256), 0, stream>>>(
            x, W, bias, idx, zp, out);
    }
}

// Round 6
// 163.624 us; speedup vs baseline: 2.2511x; 1.0094x over previous
//
#include <hip/hip_runtime.h>

#define BATCH 8
#define NPTS  12000
#define FDIM  128
#define SDIM  16
#define ODIM  128
#define KDIM  (SDIM * FDIM)      // 2048
#define MTOT  (BATCH * NPTS)     // 96000

#define BM 128
#define BK 64                    // unpadded: row stride 64 bf16 = 128 B

#define NTILES 94                // ceil(12000 / 128)
#define XELEMS (BATCH * NPTS * FDIM)   // 12,288,000
#define WELEMS (ODIM * KDIM)           // 262,144
#define XBYTES ((size_t)XELEMS * 2)
#define WBYTES ((size_t)WELEMS * 2)
#define XN4    (XELEMS / 4)
#define WN4    (WELEMS / 4)

typedef __bf16 bf16x4 __attribute__((ext_vector_type(4)));
typedef __bf16 bf16x8 __attribute__((ext_vector_type(8)));
typedef float  f32x4  __attribute__((ext_vector_type(4)));
typedef float  f32x8  __attribute__((ext_vector_type(8)));

#define AS1(p) ((const __attribute__((address_space(1))) void*)(p))
#define AS3(p) ((__attribute__((address_space(3))) void*)(p))

// ---------------- pre-pass: fp32 -> bf16 (x and W in one launch) ----------------
__global__ __launch_bounds__(256)
void cvt_f32_bf16(const float* __restrict__ x, const float* __restrict__ W,
                  __bf16* __restrict__ xb, __bf16* __restrict__ Wb) {
    int i = blockIdx.x * blockDim.x + threadIdx.x;
    const int stride = gridDim.x * blockDim.x;
    for (; i < XN4 + WN4; i += stride) {
        const float* src; __bf16* dst; int j;
        if (i < XN4) { src = x; dst = xb; j = i; }
        else         { src = W; dst = Wb; j = i - XN4; }
        const float4 v = reinterpret_cast<const float4*>(src)[j];
        bf16x4 h;
        h[0] = (__bf16)v.x; h[1] = (__bf16)v.y;
        h[2] = (__bf16)v.z; h[3] = (__bf16)v.w;
        reinterpret_cast<bf16x4*>(dst)[j] = h;
    }
}

// ---------------- main GEMM: dbuf LDS + global_load_lds + fine vmcnt ----------------
// Pipeline per iteration kt (computing tile kt from buf[kt&1]):
//   issue 8 DMA loads for tile kt+1 into buf[~kt&1]
//   s_waitcnt vmcnt(8)   <- waits only for tile kt's loads (issued last iter)
//   s_barrier            <- all waves certify buf[kt&1] filled
//   compute tile kt
//   s_barrier            <- reads done before next iter's DMA overwrites
// No __syncthreads() in the loop -> no vmcnt(0) drain; loads stay in flight.
// idx gather values live in an LDS table (ds_read/lgkmcnt) so the vmcnt
// count stays exactly 8 per tile.
__global__ __launch_bounds__(256, 2)
void spiral_gemm_bf16(const __bf16* __restrict__ xb,    // (B, N, F) bf16 (ws)
                      const __bf16* __restrict__ Wb,    // (OUT, K) bf16 (ws)
                      const float*  __restrict__ bias,  // (OUT,) fp32
                      const int*    __restrict__ idx,   // (N, S) int32
                      const float*  __restrict__ zp,    // (N,) fp32
                      float*        __restrict__ out)   // (B, N, OUT) fp32
{
    __shared__ __bf16 As[2][BM * BK];    // 2 x 16 KB
    __shared__ __bf16 Ws[2][ODIM * BK];  // 2 x 16 KB
    __shared__ int    idxS[BM * SDIM];   // 8 KB

    const int tid   = threadIdx.x;
    const int wave  = tid >> 6;
    const int lane  = tid & 63;
    const int batch = blockIdx.x & 7;          // round-robin -> same XCD per batch
    const int n0    = (blockIdx.x >> 3) * BM;

    const int lrow8 = lane >> 3;               // row within the 8-row wave pass
    const int clog  = (lane & 7) ^ lrow8;      // logical 16B chunk this lane fetches

    const __bf16* xbase = xb + (size_t)batch * (NPTS * FDIM);

    // --- preload all gather indices for this block's 128 rows into LDS ---
    {
        const int row  = tid >> 1, half = tid & 1;
        const int n    = n0 + row;
        const int nrow = n < NPTS ? n : NPTS - 1;
        const int4* s4 = reinterpret_cast<const int4*>(idx + nrow * SDIM + half * 8);
        int4* d4       = reinterpret_cast<int4*>(&idxS[row * SDIM + half * 8]);
        d4[0] = s4[0];
        d4[1] = s4[1];
    }
    __syncthreads();   // full drain OK here, once

    int rrow[4];
#pragma unroll
    for (int p = 0; p < 4; ++p) rrow[p] = (p * 4 + wave) * 8 + lrow8;

    int gCur[4], gNext[4];
#pragma unroll
    for (int p = 0; p < 4; ++p) gCur[p] = idxS[rrow[p] * SDIM + 0];

    // --- DMA issue helper: tile kt -> buf, using g[] for A rows ---
    auto issue = [&](int buf, int kt, const int* g) {
        const int f0 = (kt & 1) * BK;
#pragma unroll
        for (int p = 0; p < 4; ++p) {
            const int r0 = (p * 4 + wave) * 8;
            const __bf16* ga = xbase + (size_t)g[p] * FDIM + f0 + clog * 8;
            __builtin_amdgcn_global_load_lds(AS1(ga), AS3(&As[buf][r0 * BK]), 16, 0, 0);
            const __bf16* gw = Wb + (size_t)(r0 + lrow8) * KDIM + kt * BK + clog * 8;
            __builtin_amdgcn_global_load_lds(AS1(gw), AS3(&Ws[buf][r0 * BK]), 16, 0, 0);
        }
    };

    f32x4 acc[4][4];
#pragma unroll
    for (int i = 0; i < 4; ++i)
#pragma unroll
        for (int j = 0; j < 4; ++j)
            acc[i][j] = f32x4{0.f, 0.f, 0.f, 0.f};

    const int wm   = (wave >> 1) * 64;
    const int wn   = (wave & 1) * 64;
    const int lrow = lane & 15;
    const int quad = lane >> 4;

    auto compute = [&](int buf) {
#pragma unroll
        for (int kk = 0; kk < 2; ++kk) {
            const int ph = (kk * 4 + quad) ^ (lrow & 7);  // swizzled chunk
            bf16x8 a[4], b[4];
#pragma unroll
            for (int i = 0; i < 4; ++i)
                a[i] = *reinterpret_cast<const bf16x8*>(
                    &As[buf][(wm + i * 16 + lrow) * BK + ph * 8]);
#pragma unroll
            for (int j = 0; j < 4; ++j)
                b[j] = *reinterpret_cast<const bf16x8*>(
                    &Ws[buf][(wn + j * 16 + lrow) * BK + ph * 8]);
#pragma unroll
            for (int i = 0; i < 4; ++i)
#pragma unroll
                for (int j = 0; j < 4; ++j)
                    acc[i][j] = __builtin_amdgcn_mfma_f32_16x16x32_bf16(
                        a[i], b[j], acc[i][j], 0, 0, 0);
        }
    };

    // preamble: tile 0 (s=0, f0=0) -> buf0
    issue(0, 0, gCur);

    for (int t = 0; t < 16; ++t) {
        // ---- even kt = 2t: compute buf0, issue tile 2t+1 (s=t, f0=64) -> buf1
        issue(1, 2 * t + 1, gCur);
        asm volatile("s_waitcnt vmcnt(8)" ::: "memory");
        asm volatile("s_barrier" ::: "memory");
        if (t < 15) {
#pragma unroll
            for (int p = 0; p < 4; ++p)
                gNext[p] = idxS[rrow[p] * SDIM + t + 1];  // lgkm, hidden by compute
        }
        compute(0);
        asm volatile("s_barrier" ::: "memory");

        // ---- odd kt = 2t+1: compute buf1, issue tile 2t+2 (s=t+1, f0=0) -> buf0
        if (t < 15) {
            issue(0, 2 * t + 2, gNext);
            asm volatile("s_waitcnt vmcnt(8)" ::: "memory");
        } else {
            asm volatile("s_waitcnt vmcnt(0)" ::: "memory");
        }
        asm volatile("s_barrier" ::: "memory");
        compute(1);
        asm volatile("s_barrier" ::: "memory");
#pragma unroll
        for (int p = 0; p < 4; ++p) gCur[p] = gNext[p];
    }

    // epilogue: bias + relu + zero_padding; C/D: col=lane&15, row=quad*4+reg
#pragma unroll
    for (int i = 0; i < 4; ++i) {
#pragma unroll
        for (int r = 0; r < 4; ++r) {
            const int row = wm + i * 16 + quad * 4 + r;
            const int n   = n0 + row;
            if (n < NPTS) {
                const float z = zp[n];
                float* orow   = out + ((size_t)batch * NPTS + n) * ODIM;
#pragma unroll
                for (int j = 0; j < 4; ++j) {
                    const int col = wn + j * 16 + lrow;
                    float v = acc[i][j][r] + bias[col];
                    v = fmaxf(v, 0.f);
                    orow[col] = v * z;
                }
            }
        }
    }
}

// ---------------- fallback: fp32 direct, no ws (round-2 kernel) ----------------
#define LDA 72
__global__ __launch_bounds__(256, 2)
void spiral_gemm_fp32(const float* __restrict__ x, const float* __restrict__ W,
                      const float* __restrict__ bias, const int* __restrict__ idx,
                      const float* __restrict__ zp, float* __restrict__ out)
{
    __shared__ __bf16 Asf[BM * LDA];
    __shared__ __bf16 Wsf[ODIM * LDA];
    const int tid = threadIdx.x, wave = tid >> 6, lane = tid & 63;
    const int m0 = blockIdx.x * BM;
    const int srow = tid >> 3, schunk = tid & 7;
    int a_n[4]; const float* a_xb[4];
#pragma unroll
    for (int p = 0; p < 4; ++p) {
        int m = m0 + srow + p * 32, bb = m / NPTS;
        a_n[p] = m - bb * NPTS; a_xb[p] = x + (size_t)bb * (NPTS * FDIM);
    }
    f32x4 acc[4][4];
#pragma unroll
    for (int i = 0; i < 4; ++i)
#pragma unroll
        for (int j = 0; j < 4; ++j) acc[i][j] = f32x4{0.f,0.f,0.f,0.f};
    const int wm = (wave >> 1) * 64, wn = (wave & 1) * 64;
    const int lrow = lane & 15, quad = lane >> 4;
    for (int kt = 0; kt < KDIM / BK; ++kt) {
        const int s = kt >> 1, f0 = (kt & 1) * BK;
        __syncthreads();
#pragma unroll
        for (int p = 0; p < 4; ++p) {
            const int r = srow + p * 32;
            const int g = idx[a_n[p] * SDIM + s];
            const f32x8 v = *reinterpret_cast<const f32x8*>(
                a_xb[p] + (size_t)g * FDIM + f0 + schunk * 8);
            bf16x8 h;
#pragma unroll
            for (int e = 0; e < 8; ++e) h[e] = (__bf16)v[e];
            *reinterpret_cast<bf16x8*>(&Asf[r * LDA + schunk * 8]) = h;
            const f32x8 w = *reinterpret_cast<const f32x8*>(
                W + (size_t)r * KDIM + kt * BK + schunk * 8);
            bf16x8 hw;
#pragma unroll
            for (int e = 0; e < 8; ++e) hw[e] = (__bf16)w[e];
            *reinterpret_cast<bf16x8*>(&Wsf[r * LDA + schunk * 8]) = hw;
        }
        __syncthreads();
#pragma unroll
        for (int kk = 0; kk < 2; ++kk) {
            const int koff = kk * 32 + quad * 8;
            bf16x8 a[4], b[4];
#pragma unroll
            for (int i = 0; i < 4; ++i)
                a[i] = *reinterpret_cast<const bf16x8*>(&Asf[(wm + i*16 + lrow)*LDA + koff]);
#pragma unroll
            for (int j = 0; j < 4; ++j)
                b[j] = *reinterpret_cast<const bf16x8*>(&Wsf[(wn + j*16 + lrow)*LDA + koff]);
#pragma unroll
            for (int i = 0; i < 4; ++i)
#pragma unroll
                for (int j = 0; j < 4; ++j)
                    acc[i][j] = __builtin_amdgcn_mfma_f32_16x16x32_bf16(a[i], b[j], acc[i][j], 0,0,0);
        }
    }
#pragma unroll
    for (int i = 0; i < 4; ++i)
#pragma unroll
        for (int r = 0; r < 4; ++r) {
            const int row = wm + i * 16 + quad * 4 + r;
            const int m = m0 + row, bb = m / NPTS, nnn = m - bb * NPTS;
            const float z = zp[nnn];
            float* orow = out + (size_t)m * ODIM;
#pragma unroll
            for (int j = 0; j < 4; ++j) {
                const int col = wn + j * 16 + lrow;
                float v = acc[i][j][r] + bias[col];
                orow[col] = fmaxf(v, 0.f) * z;
            }
        }
}

extern "C" void kernel_launch(void* const* d_in, const int* in_sizes, int n_in,
                              void* d_out, int out_size, void* d_ws, size_t ws_size,
                              hipStream_t stream) {
    const float* x    = (const float*)d_in[0];
    const float* W    = (const float*)d_in[1];
    const float* bias = (const float*)d_in[2];
    const int*   idx  = (const int*)d_in[3];
    const float* zp   = (const float*)d_in[4];
    float*       out  = (float*)d_out;

    if (ws_size >= XBYTES + WBYTES) {
        __bf16* xb = (__bf16*)d_ws;
        __bf16* Wb = (__bf16*)((char*)d_ws + XBYTES);
        cvt_f32_bf16<<<dim3(1024), dim3(256), 0, stream>>>(x, W, xb, Wb);
        spiral_gemm_bf16<<<dim3(BATCH * NTILES), dim3(256), 0, stream>>>(
            xb, Wb, bias, idx, zp, out);
    } else {
        spiral_gemm_fp32<<<dim3(MTOT / BM), dim3(256), 0, stream>>>(
            x, W, bias, idx, zp, out);
    }
}